// Round 1
// baseline (369.750 us; speedup 1.0000x reference)
//
#include <hip/hip_runtime.h>
#include <stdint.h>
#include <math.h>

#define HIST_BINS   65536
#define HIST_WORDS8 16384          // uint32 words, 4 packed uint8 bins each (64 KB LDS)
#define NTHR_HIST   1024

// ---------- float <-> monotonic uint key (for atomic min/max on floats) ----------
__device__ __forceinline__ uint32_t f2key(float f){
    uint32_t u = __float_as_uint(f);
    return (u & 0x80000000u) ? ~u : (u | 0x80000000u);
}
__device__ __forceinline__ float key2f(uint32_t k){
    uint32_t u = (k & 0x80000000u) ? (k ^ 0x80000000u) : ~k;
    return __uint_as_float(u);
}

// ws layout (uint32 words):
//   [0 .. 65535]           final uint32 joint histogram (256 KB)
//   [65536 .. 65539]       minmax keys: min_x, max_x, min_y, max_y
//   [65600 ...]            per-block packed-uint8 partial histograms (nblk * 64 KB)

__global__ void init_mm_kernel(uint32_t* __restrict__ mm){
    mm[0] = 0xFFFFFFFFu;  // +inf key for min_x
    mm[1] = 0u;           // -inf key for max_x
    mm[2] = 0xFFFFFFFFu;
    mm[3] = 0u;
}

__device__ __forceinline__ void mm4(float4 a, float& mn, float& mx){
    mn = fminf(mn, fminf(fminf(a.x, a.y), fminf(a.z, a.w)));
    mx = fmaxf(mx, fmaxf(fmaxf(a.x, a.y), fmaxf(a.z, a.w)));
}

// Blocks [0, nblk_per) scan x; blocks [nblk_per, 2*nblk_per) scan y.
// Each block owns a CONTIGUOUS segment of n4/nblk_per float4s.
// Inner loop: 8 independent float4 loads spanning a dense 32 KB window
// (256 threads * 8 loads * 16 B). 256-thread blocks + launch_bounds(256,8)
// give the allocator room to keep all 8 loads in flight (<=64 VGPR,
// 32 waves/CU -> 256 KB in flight per CU).
__global__ void __launch_bounds__(256, 8)
minmax_kernel(const float4* __restrict__ x, const float4* __restrict__ y,
              uint32_t* __restrict__ mm, int n4, int nblk_per){
    int isy = (blockIdx.x >= (unsigned)nblk_per) ? 1 : 0;
    const float4* __restrict__ src = isy ? y : x;
    int bid = blockIdx.x - isy * nblk_per;

    int seg = (n4 + nblk_per - 1) / nblk_per;   // 8192 for n4 = 8.39M, nblk_per = 1024
    int start = bid * seg;
    int end = start + seg; if (end > n4) end = n4;

    float mn = INFINITY, mx = -INFINITY;
    int base = start;
    for (; base + 8 * 256 <= end; base += 8 * 256){
        int i0 = base + threadIdx.x;
        float4 v0 = src[i0];
        float4 v1 = src[i0 +  256];
        float4 v2 = src[i0 +  512];
        float4 v3 = src[i0 +  768];
        float4 v4 = src[i0 + 1024];
        float4 v5 = src[i0 + 1280];
        float4 v6 = src[i0 + 1536];
        float4 v7 = src[i0 + 1792];
        mm4(v0, mn, mx); mm4(v1, mn, mx); mm4(v2, mn, mx); mm4(v3, mn, mx);
        mm4(v4, mn, mx); mm4(v5, mn, mx); mm4(v6, mn, mx); mm4(v7, mn, mx);
    }
    for (int i = base + threadIdx.x; i < end; i += 256) mm4(src[i], mn, mx);

    #pragma unroll
    for (int off = 32; off > 0; off >>= 1){
        mn = fminf(mn, __shfl_down(mn, off, 64));
        mx = fmaxf(mx, __shfl_down(mx, off, 64));
    }
    __shared__ float smn[4], smx[4];
    int lane = threadIdx.x & 63, wid = threadIdx.x >> 6;
    if (lane == 0){ smn[wid] = mn; smx[wid] = mx; }
    __syncthreads();
    if (threadIdx.x == 0){
        for (int w = 1; w < 4; ++w){
            mn = fminf(mn, smn[w]); mx = fmaxf(mx, smx[w]);
        }
        atomicMin(&mm[isy * 2 + 0], f2key(mn));
        atomicMax(&mm[isy * 2 + 1], f2key(mx));
    }
}

__device__ __forceinline__ void bin_pair(float vx, float vy,
                                         float mnx, float sx, float mny, float sy,
                                         uint32_t* lh){
    int ix = (int)floorf((vx - mnx) * sx);
    int iy = (int)floorf((vy - mny) * sy);
    ix = ix < 0 ? 0 : (ix > 255 ? 255 : ix);
    iy = iy < 0 ? 0 : (iy > 255 ? 255 : iy);
    uint32_t bin = ((uint32_t)ix << 8) | (uint32_t)iy;
    atomicAdd(&lh[bin >> 2], 1u << ((bin & 3u) * 8u));
}

__device__ __forceinline__ void bin4(float4 a, float4 b,
                                     float mnx, float sx, float mny, float sy,
                                     uint32_t* lh){
    bin_pair(a.x, b.x, mnx, sx, mny, sy, lh);
    bin_pair(a.y, b.y, mnx, sx, mny, sy, lh);
    bin_pair(a.z, b.z, mnx, sx, mny, sy, lh);
    bin_pair(a.w, b.w, mnx, sx, mny, sy, lh);
}

// Each block owns a CONTIGUOUS segment of n4/gridDim float4s of BOTH arrays
// (x[i] must pair with y[i]). Inner loop: 4 x-loads + 4 y-loads, each set
// spanning a dense 64 KB window per array.
__global__ void __launch_bounds__(NTHR_HIST, 8)
hist_kernel(const float4* __restrict__ x, const float4* __restrict__ y,
            const uint32_t* __restrict__ mm, uint32_t* __restrict__ out32,
            int n4, int atomic_flush){
    __shared__ uint32_t lh[HIST_WORDS8];   // 64 KB: 65536 uint8 bins packed 4/word
    for (int w = threadIdx.x; w < HIST_WORDS8; w += blockDim.x) lh[w] = 0u;
    __syncthreads();

    float mnx = key2f(mm[0]);
    float sx  = 256.0f / ((key2f(mm[1]) - mnx) + 1e-8f);
    float mny = key2f(mm[2]);
    float sy  = 256.0f / ((key2f(mm[3]) - mny) + 1e-8f);

    int seg = (n4 + gridDim.x - 1) / gridDim.x;   // 16384 for n4 = 8.39M, 512 blocks
    int start = blockIdx.x * seg;
    int end = start + seg; if (end > n4) end = n4;

    int base = start;
    for (; base + 4 * 1024 <= end; base += 4 * 1024){
        int i0 = base + threadIdx.x;
        float4 a0 = x[i0], a1 = x[i0 + 1024], a2 = x[i0 + 2048], a3 = x[i0 + 3072];
        float4 b0 = y[i0], b1 = y[i0 + 1024], b2 = y[i0 + 2048], b3 = y[i0 + 3072];
        bin4(a0, b0, mnx, sx, mny, sy, lh);
        bin4(a1, b1, mnx, sx, mny, sy, lh);
        bin4(a2, b2, mnx, sx, mny, sy, lh);
        bin4(a3, b3, mnx, sx, mny, sy, lh);
    }
    for (int i = base + threadIdx.x; i < end; i += 1024){
        float4 a = x[i], b = y[i];
        bin4(a, b, mnx, sx, mny, sy, lh);
    }
    __syncthreads();

    if (!atomic_flush){
        uint32_t* part = out32 + (size_t)blockIdx.x * HIST_WORDS8;
        for (int w = threadIdx.x; w < HIST_WORDS8; w += blockDim.x) part[w] = lh[w];
    } else {
        for (int w = threadIdx.x; w < HIST_WORDS8; w += blockDim.x){
            uint32_t v = lh[w];
            if (v){
                uint32_t c0 = v & 255u, c1 = (v >> 8) & 255u, c2 = (v >> 16) & 255u, c3 = v >> 24;
                if (c0) atomicAdd(&out32[4*w + 0], c0);
                if (c1) atomicAdd(&out32[4*w + 1], c1);
                if (c2) atomicAdd(&out32[4*w + 2], c2);
                if (c3) atomicAdd(&out32[4*w + 3], c3);
            }
        }
    }
}

// 256 blocks x 1024 threads. Block b covers word-quads [b*16, b*16+16)
// (quad = uint4 = 4 packed words = 16 bins). Thread: ql = t&15 (quad within
// block, consecutive lanes -> consecutive uint4s), g = t>>4 (64 partial-groups
// of per = nparts/64 each; all loads independent -> deep ILP).
__global__ void __launch_bounds__(1024)
reduce_kernel(const uint32_t* __restrict__ partials, uint32_t* __restrict__ hist,
              int nparts){
    __shared__ uint32_t sm[64][16][16];  // [g][k][ql], 64 KB
    int t = threadIdx.x;
    int ql = t & 15, g = t >> 4;
    int per = nparts >> 6;   // 8 (nblk=512) or 4 (nblk=256)
    uint32_t c[16];
    #pragma unroll
    for (int k = 0; k < 16; ++k) c[k] = 0;
    const uint4* base = (const uint4*)partials;
    size_t qoff = (size_t)blockIdx.x * 16 + ql;
    #pragma unroll 8
    for (int j = 0; j < per; ++j){
        uint4 v = base[(size_t)(g * per + j) * (HIST_WORDS8 / 4) + qoff];
        c[ 0] += v.x & 255u; c[ 1] += (v.x >> 8) & 255u; c[ 2] += (v.x >> 16) & 255u; c[ 3] += v.x >> 24;
        c[ 4] += v.y & 255u; c[ 5] += (v.y >> 8) & 255u; c[ 6] += (v.y >> 16) & 255u; c[ 7] += v.y >> 24;
        c[ 8] += v.z & 255u; c[ 9] += (v.z >> 8) & 255u; c[10] += (v.z >> 16) & 255u; c[11] += v.z >> 24;
        c[12] += v.w & 255u; c[13] += (v.w >> 8) & 255u; c[14] += (v.w >> 16) & 255u; c[15] += v.w >> 24;
    }
    #pragma unroll
    for (int k = 0; k < 16; ++k) sm[g][k][ql] = c[k];
    __syncthreads();
    if (t < 256){
        int q2 = t & 15;      // quad within block
        int k  = t >> 4;      // bin within quad
        uint32_t s = 0;
        #pragma unroll 8
        for (int gg = 0; gg < 64; ++gg) s += sm[gg][k][q2];
        hist[((size_t)blockIdx.x * 16 + q2) * 16 + k] = s;
    }
}

__device__ double bsum1024(double v, double* red, int t){
    #pragma unroll
    for (int off = 32; off > 0; off >>= 1) v += __shfl_down(v, off, 64);
    __syncthreads();
    if ((t & 63) == 0) red[t >> 6] = v;
    __syncthreads();
    if (t == 0){
        double s = 0.0;
        for (int w = 0; w < 16; ++w) s += red[w];
        v = s;
    }
    return v;  // valid in thread 0 only
}

__global__ void __launch_bounds__(1024)
finalize_kernel(const uint32_t* __restrict__ hist, float* __restrict__ out, int n){
    __shared__ uint32_t rsum[256];      // row sums  (p_x counts)
    __shared__ uint32_t csum4[4][256];  // partial col sums
    __shared__ uint32_t csum[256];      // col sums  (p_y counts)
    __shared__ double red[16];
    int t = threadIdx.x;

    // Phase A: row sums. 4 threads per row, 16 uint4 (64 words) each, coalesced.
    {
        int r = t >> 2, q = t & 3;
        const uint4* hp = (const uint4*)(hist + r * 256 + q * 64);
        uint32_t s = 0;
        #pragma unroll
        for (int k = 0; k < 16; ++k){
            uint4 v = hp[k];
            s += v.x + v.y + v.z + v.w;
        }
        s += __shfl_down(s, 2, 64);
        s += __shfl_down(s, 1, 64);
        if (q == 0) rsum[r] = s;
    }
    // Phase B: col sums. c = t&255 (coalesced across lanes), 4 row-groups.
    {
        int c = t & 255, g = t >> 8;
        const uint32_t* hp = hist + g * 64 * 256 + c;
        uint32_t s = 0;
        #pragma unroll 8
        for (int r = 0; r < 64; ++r) s += hp[r * 256];
        csum4[g][c] = s;
    }
    __syncthreads();
    if (t < 256) csum[t] = csum4[0][t] + csum4[1][t] + csum4[2][t] + csum4[3][t];
    __syncthreads();

    const double invn = 1.0 / (double)n;
    const double dn = (double)n;

    // MI: thread handles column c = t&255, rows 4k + (t>>8). Coalesced hist reads,
    // f32 log (rel err ~1e-7 on log-values ~0.04 -> MI err <1e-8), f64 accumulation.
    double mi = 0.0;
    {
        int c = t & 255, rb = t >> 8;
        double cs = (double)csum[c];
        for (int k = 0; k < 64; ++k){
            int r = k * 4 + rb;
            uint32_t cnt = hist[r * 256 + c];
            if (cnt){
                double rs = (double)rsum[r];
                double ratio = ((double)cnt * dn) / (rs * cs);
                mi += (double)cnt * (double)logf((float)ratio);
            }
        }
        mi *= invn;
    }
    double hx = 0.0, hy = 0.0;
    if (t < 256){
        double px = (double)rsum[t] * invn;
        double py = (double)csum[t] * invn;
        hx = px * log(px + 1e-8);
        hy = py * log(py + 1e-8);
    }
    double mi_s = bsum1024(mi, red, t);
    double hx_s = bsum1024(hx, red, t);
    double hy_s = bsum1024(hy, red, t);
    if (t == 0){
        double h_x = -hx_s, h_y = -hy_s;
        double nmi = mi_s / (sqrt(h_x * h_y) + 1e-8);
        out[0] = (float)(-nmi);
    }
}

extern "C" void kernel_launch(void* const* d_in, const int* in_sizes, int n_in,
                              void* d_out, int out_size, void* d_ws, size_t ws_size,
                              hipStream_t stream){
    const float* x = (const float*)d_in[0];
    const float* y = (const float*)d_in[1];
    float* out = (float*)d_out;
    uint32_t* ws = (uint32_t*)d_ws;
    uint32_t* hist = ws;                       // 65536 uint32
    uint32_t* mm = ws + HIST_BINS;             // 4 uint32
    uint32_t* partials = ws + HIST_BINS + 64;  // nblk * 16384 uint32

    int n  = in_sizes[0];
    int n4 = n / 4;

    size_t need512 = ((size_t)HIST_BINS + 64 + (size_t)512 * HIST_WORDS8) * 4;
    size_t need256 = ((size_t)HIST_BINS + 64 + (size_t)256 * HIST_WORDS8) * 4;
    int nblk, atomic_flush;
    if (ws_size >= need512)      { nblk = 512; atomic_flush = 0; }
    else if (ws_size >= need256) { nblk = 256; atomic_flush = 0; }
    else                         { nblk = 512; atomic_flush = 1; }

    if (atomic_flush)
        hipMemsetAsync(hist, 0, HIST_BINS * sizeof(uint32_t), stream);
    init_mm_kernel<<<1, 1, 0, stream>>>(mm);
    minmax_kernel<<<2048, 256, 0, stream>>>((const float4*)x, (const float4*)y, mm, n4, 1024);
    hist_kernel<<<nblk, NTHR_HIST, 0, stream>>>((const float4*)x, (const float4*)y, mm,
                                                atomic_flush ? hist : partials, n4, atomic_flush);
    if (!atomic_flush)
        reduce_kernel<<<256, 1024, 0, stream>>>(partials, hist, nblk);
    finalize_kernel<<<1, 1024, 0, stream>>>(hist, out, n);
}

// Round 2
// 368.101 us; speedup vs baseline: 1.0045x; 1.0045x over previous
//
#include <hip/hip_runtime.h>
#include <stdint.h>
#include <math.h>

#define HIST_BINS   65536
#define HIST_WORDS8 16384          // uint32 words, 4 packed uint8 bins each (64 KB LDS)
#define NTHR_HIST   1024

typedef float f32x4 __attribute__((ext_vector_type(4)));

// Explicit async global load: volatile asm order is preserved by the compiler,
// so 8 of these issue back-to-back with no intervening waitcnt -> 8 loads in
// flight per wave (the compiler refuses to do this from C++ source; it
// serialized to ~1 outstanding load, VGPR_Count=20, in rounds 0-1).
__device__ __forceinline__ f32x4 gload4(const float4* p){
    f32x4 r;
    asm volatile("global_load_dwordx4 %0, %1, off" : "=&v"(r) : "v"(p) : "memory");
    return r;
}

// Counted drain + scheduling fence (guide rule 18: hipcc will hoist consumers
// past an inline-asm waitcnt unless a sched_barrier(0) follows it).
#define VWAIT(N) do { asm volatile("s_waitcnt vmcnt(" #N ")" ::: "memory"); \
                      __builtin_amdgcn_sched_barrier(0); } while (0)

// ---------- float <-> monotonic uint key (for atomic min/max on floats) ----------
__device__ __forceinline__ uint32_t f2key(float f){
    uint32_t u = __float_as_uint(f);
    return (u & 0x80000000u) ? ~u : (u | 0x80000000u);
}
__device__ __forceinline__ float key2f(uint32_t k){
    uint32_t u = (k & 0x80000000u) ? (k ^ 0x80000000u) : ~k;
    return __uint_as_float(u);
}

// ws layout (uint32 words):
//   [0 .. 65535]           final uint32 joint histogram (256 KB)
//   [65536 .. 65539]       minmax keys: min_x, max_x, min_y, max_y
//   [65600 ...]            per-block packed-uint8 partial histograms (nblk * 64 KB)

__global__ void init_mm_kernel(uint32_t* __restrict__ mm){
    mm[0] = 0xFFFFFFFFu;  // +inf key for min_x
    mm[1] = 0u;           // -inf key for max_x
    mm[2] = 0xFFFFFFFFu;
    mm[3] = 0u;
}

__device__ __forceinline__ void mm4(f32x4 a, float& mn, float& mx){
    mn = fminf(mn, fminf(fminf(a.x, a.y), fminf(a.z, a.w)));
    mx = fmaxf(mx, fmaxf(fmaxf(a.x, a.y), fmaxf(a.z, a.w)));
}

// Blocks [0, nblk_per) scan x; blocks [nblk_per, 2*nblk_per) scan y.
// Contiguous per-block segment; 8 asm loads in flight, pipelined vmcnt drain.
__global__ void __launch_bounds__(256, 8)
minmax_kernel(const float4* __restrict__ x, const float4* __restrict__ y,
              uint32_t* __restrict__ mm, int n4, int nblk_per){
    int isy = (blockIdx.x >= (unsigned)nblk_per) ? 1 : 0;
    const float4* __restrict__ src = isy ? y : x;
    int bid = blockIdx.x - isy * nblk_per;

    int seg = (n4 + nblk_per - 1) / nblk_per;   // 8192 for n4 = 8.39M, nblk_per = 1024
    int start = bid * seg;
    int end = start + seg; if (end > n4) end = n4;

    float mn = INFINITY, mx = -INFINITY;
    int base = start;
    for (; base + 8 * 256 <= end; base += 8 * 256){
        const float4* p = src + base + threadIdx.x;
        f32x4 v0 = gload4(p);
        f32x4 v1 = gload4(p +  256);
        f32x4 v2 = gload4(p +  512);
        f32x4 v3 = gload4(p +  768);
        f32x4 v4 = gload4(p + 1024);
        f32x4 v5 = gload4(p + 1280);
        f32x4 v6 = gload4(p + 1536);
        f32x4 v7 = gload4(p + 1792);
        VWAIT(7); mm4(v0, mn, mx);
        VWAIT(6); mm4(v1, mn, mx);
        VWAIT(5); mm4(v2, mn, mx);
        VWAIT(4); mm4(v3, mn, mx);
        VWAIT(3); mm4(v4, mn, mx);
        VWAIT(2); mm4(v5, mn, mx);
        VWAIT(1); mm4(v6, mn, mx);
        VWAIT(0); mm4(v7, mn, mx);
    }
    for (int i = base + threadIdx.x; i < end; i += 256){
        f32x4 v = gload4(src + i);
        VWAIT(0); mm4(v, mn, mx);
    }

    #pragma unroll
    for (int off = 32; off > 0; off >>= 1){
        mn = fminf(mn, __shfl_down(mn, off, 64));
        mx = fmaxf(mx, __shfl_down(mx, off, 64));
    }
    __shared__ float smn[4], smx[4];
    int lane = threadIdx.x & 63, wid = threadIdx.x >> 6;
    if (lane == 0){ smn[wid] = mn; smx[wid] = mx; }
    __syncthreads();
    if (threadIdx.x == 0){
        for (int w = 1; w < 4; ++w){
            mn = fminf(mn, smn[w]); mx = fmaxf(mx, smx[w]);
        }
        atomicMin(&mm[isy * 2 + 0], f2key(mn));
        atomicMax(&mm[isy * 2 + 1], f2key(mx));
    }
}

__device__ __forceinline__ void bin_pair(float vx, float vy,
                                         float mnx, float sx, float mny, float sy,
                                         uint32_t* lh){
    int ix = (int)floorf((vx - mnx) * sx);
    int iy = (int)floorf((vy - mny) * sy);
    ix = ix < 0 ? 0 : (ix > 255 ? 255 : ix);
    iy = iy < 0 ? 0 : (iy > 255 ? 255 : iy);
    uint32_t bin = ((uint32_t)ix << 8) | (uint32_t)iy;
    atomicAdd(&lh[bin >> 2], 1u << ((bin & 3u) * 8u));
}

__device__ __forceinline__ void bin4(f32x4 a, f32x4 b,
                                     float mnx, float sx, float mny, float sy,
                                     uint32_t* lh){
    bin_pair(a.x, b.x, mnx, sx, mny, sy, lh);
    bin_pair(a.y, b.y, mnx, sx, mny, sy, lh);
    bin_pair(a.z, b.z, mnx, sx, mny, sy, lh);
    bin_pair(a.w, b.w, mnx, sx, mny, sy, lh);
}

// Contiguous per-block segment of BOTH arrays (x[i] pairs with y[i]).
// 8 asm loads in flight (x/y interleaved), pairs drain at vmcnt(6/4/2/0).
__global__ void __launch_bounds__(NTHR_HIST, 8)
hist_kernel(const float4* __restrict__ x, const float4* __restrict__ y,
            const uint32_t* __restrict__ mm, uint32_t* __restrict__ out32,
            int n4, int atomic_flush){
    __shared__ uint32_t lh[HIST_WORDS8];   // 64 KB: 65536 uint8 bins packed 4/word
    for (int w = threadIdx.x; w < HIST_WORDS8; w += blockDim.x) lh[w] = 0u;
    __syncthreads();

    float mnx = key2f(mm[0]);
    float sx  = 256.0f / ((key2f(mm[1]) - mnx) + 1e-8f);
    float mny = key2f(mm[2]);
    float sy  = 256.0f / ((key2f(mm[3]) - mny) + 1e-8f);

    int seg = (n4 + gridDim.x - 1) / gridDim.x;   // 16384 for n4 = 8.39M, 512 blocks
    int start = blockIdx.x * seg;
    int end = start + seg; if (end > n4) end = n4;

    int base = start;
    for (; base + 4 * 1024 <= end; base += 4 * 1024){
        const float4* px = x + base + threadIdx.x;
        const float4* py = y + base + threadIdx.x;
        f32x4 a0 = gload4(px);
        f32x4 b0 = gload4(py);
        f32x4 a1 = gload4(px + 1024);
        f32x4 b1 = gload4(py + 1024);
        f32x4 a2 = gload4(px + 2048);
        f32x4 b2 = gload4(py + 2048);
        f32x4 a3 = gload4(px + 3072);
        f32x4 b3 = gload4(py + 3072);
        VWAIT(6); bin4(a0, b0, mnx, sx, mny, sy, lh);
        VWAIT(4); bin4(a1, b1, mnx, sx, mny, sy, lh);
        VWAIT(2); bin4(a2, b2, mnx, sx, mny, sy, lh);
        VWAIT(0); bin4(a3, b3, mnx, sx, mny, sy, lh);
    }
    for (int i = base + threadIdx.x; i < end; i += 1024){
        f32x4 a = gload4(x + i);
        f32x4 b = gload4(y + i);
        VWAIT(0); bin4(a, b, mnx, sx, mny, sy, lh);
    }
    __syncthreads();

    if (!atomic_flush){
        uint32_t* part = out32 + (size_t)blockIdx.x * HIST_WORDS8;
        for (int w = threadIdx.x; w < HIST_WORDS8; w += blockDim.x) part[w] = lh[w];
    } else {
        for (int w = threadIdx.x; w < HIST_WORDS8; w += blockDim.x){
            uint32_t v = lh[w];
            if (v){
                uint32_t c0 = v & 255u, c1 = (v >> 8) & 255u, c2 = (v >> 16) & 255u, c3 = v >> 24;
                if (c0) atomicAdd(&out32[4*w + 0], c0);
                if (c1) atomicAdd(&out32[4*w + 1], c1);
                if (c2) atomicAdd(&out32[4*w + 2], c2);
                if (c3) atomicAdd(&out32[4*w + 3], c3);
            }
        }
    }
}

// 256 blocks x 1024 threads. Block b covers word-quads [b*16, b*16+16)
// (quad = uint4 = 4 packed words = 16 bins). Thread: ql = t&15 (quad within
// block, consecutive lanes -> consecutive uint4s), g = t>>4 (64 partial-groups
// of per = nparts/64 each; all loads independent -> deep ILP).
__global__ void __launch_bounds__(1024)
reduce_kernel(const uint32_t* __restrict__ partials, uint32_t* __restrict__ hist,
              int nparts){
    __shared__ uint32_t sm[64][16][16];  // [g][k][ql], 64 KB
    int t = threadIdx.x;
    int ql = t & 15, g = t >> 4;
    int per = nparts >> 6;   // 8 (nblk=512) or 4 (nblk=256)
    uint32_t c[16];
    #pragma unroll
    for (int k = 0; k < 16; ++k) c[k] = 0;
    const uint4* base = (const uint4*)partials;
    size_t qoff = (size_t)blockIdx.x * 16 + ql;
    #pragma unroll 8
    for (int j = 0; j < per; ++j){
        uint4 v = base[(size_t)(g * per + j) * (HIST_WORDS8 / 4) + qoff];
        c[ 0] += v.x & 255u; c[ 1] += (v.x >> 8) & 255u; c[ 2] += (v.x >> 16) & 255u; c[ 3] += v.x >> 24;
        c[ 4] += v.y & 255u; c[ 5] += (v.y >> 8) & 255u; c[ 6] += (v.y >> 16) & 255u; c[ 7] += v.y >> 24;
        c[ 8] += v.z & 255u; c[ 9] += (v.z >> 8) & 255u; c[10] += (v.z >> 16) & 255u; c[11] += v.z >> 24;
        c[12] += v.w & 255u; c[13] += (v.w >> 8) & 255u; c[14] += (v.w >> 16) & 255u; c[15] += v.w >> 24;
    }
    #pragma unroll
    for (int k = 0; k < 16; ++k) sm[g][k][ql] = c[k];
    __syncthreads();
    if (t < 256){
        int q2 = t & 15;      // quad within block
        int k  = t >> 4;      // bin within quad
        uint32_t s = 0;
        #pragma unroll 8
        for (int gg = 0; gg < 64; ++gg) s += sm[gg][k][q2];
        hist[((size_t)blockIdx.x * 16 + q2) * 16 + k] = s;
    }
}

__device__ double bsum1024(double v, double* red, int t){
    #pragma unroll
    for (int off = 32; off > 0; off >>= 1) v += __shfl_down(v, off, 64);
    __syncthreads();
    if ((t & 63) == 0) red[t >> 6] = v;
    __syncthreads();
    if (t == 0){
        double s = 0.0;
        for (int w = 0; w < 16; ++w) s += red[w];
        v = s;
    }
    return v;  // valid in thread 0 only
}

__global__ void __launch_bounds__(1024)
finalize_kernel(const uint32_t* __restrict__ hist, float* __restrict__ out, int n){
    __shared__ uint32_t rsum[256];      // row sums  (p_x counts)
    __shared__ uint32_t csum4[4][256];  // partial col sums
    __shared__ uint32_t csum[256];      // col sums  (p_y counts)
    __shared__ double red[16];
    int t = threadIdx.x;

    // Phase A: row sums. 4 threads per row, 16 uint4 (64 words) each, coalesced.
    {
        int r = t >> 2, q = t & 3;
        const uint4* hp = (const uint4*)(hist + r * 256 + q * 64);
        uint32_t s = 0;
        #pragma unroll
        for (int k = 0; k < 16; ++k){
            uint4 v = hp[k];
            s += v.x + v.y + v.z + v.w;
        }
        s += __shfl_down(s, 2, 64);
        s += __shfl_down(s, 1, 64);
        if (q == 0) rsum[r] = s;
    }
    // Phase B: col sums. c = t&255 (coalesced across lanes), 4 row-groups.
    {
        int c = t & 255, g = t >> 8;
        const uint32_t* hp = hist + g * 64 * 256 + c;
        uint32_t s = 0;
        #pragma unroll 8
        for (int r = 0; r < 64; ++r) s += hp[r * 256];
        csum4[g][c] = s;
    }
    __syncthreads();
    if (t < 256) csum[t] = csum4[0][t] + csum4[1][t] + csum4[2][t] + csum4[3][t];
    __syncthreads();

    const double invn = 1.0 / (double)n;
    const double dn = (double)n;

    // MI: thread handles column c = t&255, rows 4k + (t>>8). Coalesced hist reads,
    // f32 log (rel err ~1e-7 on log-values ~0.04 -> MI err <1e-8), f64 accumulation.
    double mi = 0.0;
    {
        int c = t & 255, rb = t >> 8;
        double cs = (double)csum[c];
        for (int k = 0; k < 64; ++k){
            int r = k * 4 + rb;
            uint32_t cnt = hist[r * 256 + c];
            if (cnt){
                double rs = (double)rsum[r];
                double ratio = ((double)cnt * dn) / (rs * cs);
                mi += (double)cnt * (double)logf((float)ratio);
            }
        }
        mi *= invn;
    }
    double hx = 0.0, hy = 0.0;
    if (t < 256){
        double px = (double)rsum[t] * invn;
        double py = (double)csum[t] * invn;
        hx = px * log(px + 1e-8);
        hy = py * log(py + 1e-8);
    }
    double mi_s = bsum1024(mi, red, t);
    double hx_s = bsum1024(hx, red, t);
    double hy_s = bsum1024(hy, red, t);
    if (t == 0){
        double h_x = -hx_s, h_y = -hy_s;
        double nmi = mi_s / (sqrt(h_x * h_y) + 1e-8);
        out[0] = (float)(-nmi);
    }
}

extern "C" void kernel_launch(void* const* d_in, const int* in_sizes, int n_in,
                              void* d_out, int out_size, void* d_ws, size_t ws_size,
                              hipStream_t stream){
    const float* x = (const float*)d_in[0];
    const float* y = (const float*)d_in[1];
    float* out = (float*)d_out;
    uint32_t* ws = (uint32_t*)d_ws;
    uint32_t* hist = ws;                       // 65536 uint32
    uint32_t* mm = ws + HIST_BINS;             // 4 uint32
    uint32_t* partials = ws + HIST_BINS + 64;  // nblk * 16384 uint32

    int n  = in_sizes[0];
    int n4 = n / 4;

    size_t need512 = ((size_t)HIST_BINS + 64 + (size_t)512 * HIST_WORDS8) * 4;
    size_t need256 = ((size_t)HIST_BINS + 64 + (size_t)256 * HIST_WORDS8) * 4;
    int nblk, atomic_flush;
    if (ws_size >= need512)      { nblk = 512; atomic_flush = 0; }
    else if (ws_size >= need256) { nblk = 256; atomic_flush = 0; }
    else                         { nblk = 512; atomic_flush = 1; }

    if (atomic_flush)
        hipMemsetAsync(hist, 0, HIST_BINS * sizeof(uint32_t), stream);
    init_mm_kernel<<<1, 1, 0, stream>>>(mm);
    minmax_kernel<<<2048, 256, 0, stream>>>((const float4*)x, (const float4*)y, mm, n4, 1024);
    hist_kernel<<<nblk, NTHR_HIST, 0, stream>>>((const float4*)x, (const float4*)y, mm,
                                                atomic_flush ? hist : partials, n4, atomic_flush);
    if (!atomic_flush)
        reduce_kernel<<<256, 1024, 0, stream>>>(partials, hist, nblk);
    finalize_kernel<<<1, 1024, 0, stream>>>(hist, out, n);
}